// Round 9
// baseline (1141.294 us; speedup 1.0000x reference)
//
#include <hip/hip_runtime.h>
#include <hip/hip_bf16.h>

#define B_DIM 8
#define S_DIM 1024
#define D_DIM 1024
#define N_DIM 256
#define M_ROWS (B_DIM * S_DIM) /* 8192 */

typedef __attribute__((ext_vector_type(8))) short bf16x8;
typedef __attribute__((ext_vector_type(8))) unsigned short u16x8;
typedef __attribute__((ext_vector_type(4))) unsigned short u16x4;
typedef __attribute__((ext_vector_type(4))) float f32x4;

static __device__ __forceinline__ unsigned short f2bf(float f) {
  union { __hip_bfloat16 h; unsigned short s; } u;
  u.h = __float2bfloat16(f);
  return u.s;
}

static __device__ __forceinline__ float log1p_fast(float x) {
  return __logf(1.0f + x);
}

// lane^1 / lane^2 exchange via DPP quad_perm — pure VALU.
static __device__ __forceinline__ float dpp_swap1(float x) {
  int r = __builtin_amdgcn_update_dpp(0, __builtin_bit_cast(int, x),
                                      0xB1, 0xF, 0xF, true);
  return __builtin_bit_cast(float, r);
}
static __device__ __forceinline__ float dpp_swap2(float x) {
  int r = __builtin_amdgcn_update_dpp(0, __builtin_bit_cast(int, x),
                                      0x4E, 0xF, 0xF, true);
  return __builtin_bit_cast(float, r);
}

static __device__ __forceinline__ float hsum4(f32x4 v) {
  return (v[0] + v[1]) + (v[2] + v[3]);
}

// ---------------------------------------------------------------------------
// GEMM1: KV[8192][512] = x[8192][1024] @ [Wk;Wv]([512][1024])^T   (bf16 MFMA)
// ---------------------------------------------------------------------------
__global__ __launch_bounds__(256) void gemm_kv(const float* __restrict__ x,
                                               const float* __restrict__ Wk,
                                               const float* __restrict__ Wv,
                                               float* __restrict__ KV) {
  __shared__ unsigned short lsA[128 * 40];
  __shared__ unsigned short lsB[128 * 40];
  const int tid = threadIdx.x;
  const int row0 = blockIdx.y * 128;
  const int col0 = blockIdx.x * 128;
  const float* Bsrc = (col0 < 256) ? (Wk + (size_t)col0 * 1024)
                                   : (Wv + (size_t)(col0 - 256) * 1024);
  const int sr = tid >> 1, sh = tid & 1;
  const float* ap = x + (size_t)(row0 + sr) * 1024 + sh * 16;
  const float* bp = Bsrc + (size_t)sr * 1024 + sh * 16;
  unsigned short* wa = &lsA[sr * 40 + sh * 16];
  unsigned short* wb = &lsB[sr * 40 + sh * 16];

  const int lane = tid & 63;
  const int w = tid >> 6, wr = w >> 1, wc = w & 1;
  const int fr = lane & 15, fk = lane >> 4;

  f32x4 acc[4][4];
#pragma unroll
  for (int m = 0; m < 4; ++m)
#pragma unroll
    for (int n = 0; n < 4; ++n) acc[m][n] = (f32x4){0.f, 0.f, 0.f, 0.f};

  for (int kt = 0; kt < 32; ++kt) {
    const float* a = ap + kt * 32;
    const float* b = bp + kt * 32;
    f32x4 A0 = *(const f32x4*)(a + 0), A1 = *(const f32x4*)(a + 4);
    f32x4 A2 = *(const f32x4*)(a + 8), A3 = *(const f32x4*)(a + 12);
    f32x4 B0 = *(const f32x4*)(b + 0), B1 = *(const f32x4*)(b + 4);
    f32x4 B2 = *(const f32x4*)(b + 8), B3 = *(const f32x4*)(b + 12);
    u16x8 pa0, pa1, pb0, pb1;
#pragma unroll
    for (int e = 0; e < 4; ++e) {
      pa0[e] = f2bf(A0[e]); pa0[e + 4] = f2bf(A1[e]);
      pa1[e] = f2bf(A2[e]); pa1[e + 4] = f2bf(A3[e]);
      pb0[e] = f2bf(B0[e]); pb0[e + 4] = f2bf(B1[e]);
      pb1[e] = f2bf(B2[e]); pb1[e + 4] = f2bf(B3[e]);
    }
    *(u16x8*)wa = pa0; *(u16x8*)(wa + 8) = pa1;
    *(u16x8*)wb = pb0; *(u16x8*)(wb + 8) = pb1;
    __syncthreads();
    bf16x8 af[4], bfr[4];
#pragma unroll
    for (int m = 0; m < 4; ++m)
      af[m] = *(const bf16x8*)(&lsA[(wr * 64 + m * 16 + fr) * 40 + fk * 8]);
#pragma unroll
    for (int n = 0; n < 4; ++n)
      bfr[n] = *(const bf16x8*)(&lsB[(wc * 64 + n * 16 + fr) * 40 + fk * 8]);
#pragma unroll
    for (int m = 0; m < 4; ++m)
#pragma unroll
      for (int n = 0; n < 4; ++n)
        acc[m][n] = __builtin_amdgcn_mfma_f32_16x16x32_bf16(af[m], bfr[n],
                                                            acc[m][n], 0, 0, 0);
    __syncthreads();
  }
#pragma unroll
  for (int m = 0; m < 4; ++m)
#pragma unroll
    for (int n = 0; n < 4; ++n) {
      const int col = col0 + wc * 64 + n * 16 + fr;
#pragma unroll
      for (int r = 0; r < 4; ++r) {
        const int row = row0 + wr * 64 + m * 16 + fk * 4 + r;
        KV[(size_t)row * 512 + col] = acc[m][n][r];
      }
    }
}

// ---------------------------------------------------------------------------
// gate[8192] = sigmoid(x @ Wg^T + bg)
// ---------------------------------------------------------------------------
__global__ __launch_bounds__(256) void gate_kernel(const float* __restrict__ x,
                                                   const float* __restrict__ Wg,
                                                   const float* __restrict__ bg,
                                                   float* __restrict__ gate) {
  const int row = blockIdx.x * 4 + (threadIdx.x >> 6);
  const int lane = threadIdx.x & 63;
  const f32x4* xr = (const f32x4*)(x + (size_t)row * 1024);
  const f32x4* wg = (const f32x4*)Wg;
  float s = 0.f;
#pragma unroll
  for (int c = 0; c < 4; ++c) {
    f32x4 a = xr[lane + 64 * c];
    f32x4 wv = wg[lane + 64 * c];
    s += a[0] * wv[0] + a[1] * wv[1] + a[2] * wv[2] + a[3] * wv[3];
  }
#pragma unroll
  for (int off = 32; off >= 1; off >>= 1) s += __shfl_xor(s, off, 64);
  if (lane == 0) gate[row] = 1.f / (1.f + __expf(-(s + bg[0])));
}

// ---------------------------------------------------------------------------
// WoP[d][i*16+k] = Wo[d][k*16+i]  (involution permute of columns)
// ---------------------------------------------------------------------------
__global__ __launch_bounds__(256) void wo_perm(const float* __restrict__ Wo,
                                               float* __restrict__ WoP) {
  const int d = blockIdx.x;
  const int c = threadIdx.x;
  WoP[(size_t)d * 256 + c] = Wo[(size_t)d * 256 + ((c & 15) * 16 + (c >> 4))];
}

// ---------------------------------------------------------------------------
// actv[b][s][i] = || K[b,s,i,:] ||  (scan-independent, precomputed)
// ---------------------------------------------------------------------------
__global__ __launch_bounds__(256) void act_kernel(const float* __restrict__ KV,
                                                  float* __restrict__ actv) {
  const int idx = blockIdx.x * 256 + threadIdx.x;  // 0..131071
  const int bs = idx >> 4, i = idx & 15;
  const f32x4* p = (const f32x4*)(KV + (size_t)bs * 512 + i * 16);
  f32x4 a0 = p[0], a1 = p[1], a2 = p[2], a3 = p[3];
  f32x4 s = a0 * a0 + a1 * a1 + a2 * a2 + a3 * a3;
  actv[idx] = sqrtf(hsum4(s));
}

// ---------------------------------------------------------------------------
// Sequential scan: 1 block = 1 WAVE per batch (64 lanes), barrier-free.
// lane = (i, g): i = lane>>2 row, g = lane&3 → owns full columns k0..k0+3
// (all 16 j) of w1[i] and w2[i].  No w2^T: grad_h via column-partials + DPP
// quad reduction.  Only LDS use: hidden transpose + deferred err^2 partials,
// both wave-local (lgkmcnt only, no s_barrier).
// ---------------------------------------------------------------------------
__global__ __launch_bounds__(64) void scan_kernel(const float* __restrict__ KV,
                                                  const float* __restrict__ gate,
                                                  const float* __restrict__ actv,
                                                  unsigned short* __restrict__ ysbf,
                                                  float* __restrict__ err_out) {
  const int b = blockIdx.x;
  const int lane = threadIdx.x;   // 0..63
  const int i = lane >> 2;        // 0..15
  const int g = lane & 3;         // 0..3
  const int k0 = g * 4;

  __shared__ __align__(16) float hidT[2][16 * 20];  // T[p][q]=hidden[q][p], stride 20
  __shared__ __align__(16) float red[2][16];

  // w1v[c][q][e] = w1[i][4q+e][k0+c], same for w2v. Init to identity.
  f32x4 w1v[4][4], w2v[4][4];
#pragma unroll
  for (int c = 0; c < 4; ++c)
#pragma unroll
    for (int q = 0; q < 4; ++q) {
      f32x4 v;
#pragma unroll
      for (int e = 0; e < 4; ++e) v[e] = ((4 * q + e) == (k0 + c)) ? 1.f : 0.f;
      w1v[c][q] = v; w2v[c][q] = v;
    }
  float strength = 0.f, last_seen = 0.f, pend = 0.f;

  const float* Kb = KV + (size_t)b * S_DIM * 512;
  const float* Gb = gate + (size_t)b * S_DIM;
  const float* Ab = actv + (size_t)b * S_DIM * 16;
  unsigned short* Yb = ysbf + (size_t)b * S_DIM * 256;
  float* Eb = err_out + (size_t)b * S_DIM;

  // 2-deep ping-pong prefetch
  f32x4 ktA[4], ktB[4], vtA, vtB;
  float gA, gB, aA, aB;
  {
    const f32x4* p0 = (const f32x4*)(Kb + i * 16);
    ktA[0] = p0[0]; ktA[1] = p0[1]; ktA[2] = p0[2]; ktA[3] = p0[3];
    vtA = *(const f32x4*)(Kb + 256 + i * 16 + k0);
    gA = Gb[0]; aA = Ab[i];
    const f32x4* p1 = (const f32x4*)(Kb + 512 + i * 16);
    ktB[0] = p1[0]; ktB[1] = p1[1]; ktB[2] = p1[2]; ktB[3] = p1[3];
    vtB = *(const f32x4*)(Kb + 512 + 256 + i * 16 + k0);
    gB = Gb[1]; aB = Ab[16 + i];
  }

  auto step = [&](int s, f32x4 (&kt)[4], f32x4& vt4, float& gv, float& av) {
    const int pb = s & 1;
    const float t = (float)(s + 1);

    // hidden[i][k0+c] = kt_row_i . w1col(k0+c)
    float hid[4];
#pragma unroll
    for (int c = 0; c < 4; ++c) {
      f32x4 acc = kt[0] * w1v[c][0];
      acc += kt[1] * w1v[c][1];
      acc += kt[2] * w1v[c][2];
      acc += kt[3] * w1v[c][3];
      hid[c] = hsum4(acc);
    }
    // write transposed: T[k][i]
#pragma unroll
    for (int c = 0; c < 4; ++c) hidT[pb][(k0 + c) * 20 + i] = hid[c];
    asm volatile("s_waitcnt lgkmcnt(0)" ::: "memory");

    // hj[q][e] = hidden[4q+e][i]  (row i of T)
    f32x4 hj[4];
#pragma unroll
    for (int q = 0; q < 4; ++q) hj[q] = *(const f32x4*)&hidT[pb][i * 20 + q * 4];

    // deferred strength update (err_norm of step s-1)
    if (s > 0) {
      const f32x4* rp = (const f32x4*)&red[1 - pb][0];
      const f32x4 rs = (rp[0] + rp[1]) + (rp[2] + rp[3]);
      const float en = sqrtf(hsum4(rs));
      strength += pend * __builtin_amdgcn_rcpf(1.f + en);
      if (lane == 0) Eb[s - 1] = en;
    }
    const float delta = t - last_seen;
    const float m_pre = fmaxf(log1p_fast(delta * 0.1f), 1.f);
    const float df = 0.05f * m_pre * __builtin_amdgcn_rcpf(m_pre + strength);
    const float am = 1.f - df;

    // vt_pred[i][k0+c] = hj . w2col(k0+c)
    float vpc[4], errc[4];
#pragma unroll
    for (int c = 0; c < 4; ++c) {
      f32x4 acc = hj[0] * w2v[c][0];
      acc += hj[1] * w2v[c][1];
      acc += hj[2] * w2v[c][2];
      acc += hj[3] * w2v[c][3];
      vpc[c] = hsum4(acc);
      errc[c] = vpc[c] - vt4[c];
    }
    // Y store (permuted layout [i*16+k]); coalesced 8B/lane
    {
      u16x4 yv = {f2bf(vpc[0]), f2bf(vpc[1]), f2bf(vpc[2]), f2bf(vpc[3])};
      *(u16x4*)(Yb + (size_t)s * 256 + i * 16 + k0) = yv;
    }

    // grad_h partials: pg[q][e] (pre-reduce) = sum_c err[k0+c]*w2[i][4q+e][k0+c]
    f32x4 pg[4];
#pragma unroll
    for (int q = 0; q < 4; ++q) {
      f32x4 acc = errc[0] * w2v[0][q];
      acc += errc[1] * w2v[1][q];
      acc += errc[2] * w2v[2][q];
      acc += errc[3] * w2v[3][q];
      pg[q] = acc;
    }
    // own err^2 partial
    float pe = errc[0] * errc[0] + errc[1] * errc[1] +
               errc[2] * errc[2] + errc[3] * errc[3];
    // reduce across the 4 lanes of row i (g dim) via DPP quad perms
#pragma unroll
    for (int q = 0; q < 4; ++q)
#pragma unroll
      for (int e = 0; e < 4; ++e) pg[q][e] += dpp_swap1(pg[q][e]);
    pe += dpp_swap1(pe);
#pragma unroll
    for (int q = 0; q < 4; ++q)
#pragma unroll
      for (int e = 0; e < 4; ++e) pg[q][e] += dpp_swap2(pg[q][e]);
    pe += dpp_swap2(pe);
    if (g == 0) red[pb][i] = pe;  // per-row err^2 (consumed next step)

    // gh for own columns: gh[k0+c] = pg[g][c]
    const f32x4 gh4 = (g == 0) ? pg[0] : (g == 1) ? pg[1] : (g == 2) ? pg[2] : pg[3];

    const float slr = 0.1f * gv;
    // identity-decay addend: df lands at element [c] of chunk q==g
    float dfq[4];
#pragma unroll
    for (int q = 0; q < 4; ++q) dfq[q] = (q == g) ? df : 0.f;

#pragma unroll
    for (int c = 0; c < 4; ++c) {
      const float nsg = -slr * gh4[c];
      const float nse = -slr * errc[c];
#pragma unroll
      for (int q = 0; q < 4; ++q) {
        f32x4 a = w1v[c][q] + nsg * kt[q];
        a = a * am;
        a[c] += dfq[q];
        w1v[c][q] = a;
        f32x4 b2 = w2v[c][q] + nse * hj[q];
        b2 = b2 * am;
        b2[c] += dfq[q];
        w2v[c][q] = b2;
      }
    }

    pend = log1p_fast(delta) * av * gv * 0.05f;
    if (av > 0.1f) last_seen = t;

    // prefetch step s+2 (stray tail reads stay inside ws)
    {
      const float* base = Kb + (size_t)(s + 2) * 512;
      const f32x4* kp = (const f32x4*)(base + i * 16);
      kt[0] = kp[0]; kt[1] = kp[1]; kt[2] = kp[2]; kt[3] = kp[3];
      vt4 = *(const f32x4*)(base + 256 + i * 16 + k0);
      gv = Gb[s + 2];
      av = Ab[(size_t)(s + 2) * 16 + i];
    }
  };

  for (int s = 0; s < S_DIM; s += 2) {
    step(s, ktA, vtA, gA, aA);
    step(s + 1, ktB, vtB, gB, aB);
  }
  asm volatile("s_waitcnt lgkmcnt(0)" ::: "memory");
  if (lane == 0) {
    const f32x4* rp = (const f32x4*)&red[1][0];  // s=1023 parity = 1
    const f32x4 rs = (rp[0] + rp[1]) + (rp[2] + rp[3]);
    Eb[S_DIM - 1] = sqrtf(hsum4(rs));
  }
}

// ---------------------------------------------------------------------------
// GEMM2: out[8192][1024] = ysP[8192][256](bf16) @ WoP([1024][256])^T + bo
// ---------------------------------------------------------------------------
__global__ __launch_bounds__(256) void gemm_out(const unsigned short* __restrict__ ysbf,
                                                const float* __restrict__ WoP,
                                                const float* __restrict__ bo,
                                                float* __restrict__ out) {
  __shared__ unsigned short lsA[128 * 40];
  __shared__ unsigned short lsB[128 * 40];
  const int tid = threadIdx.x;
  const int row0 = blockIdx.y * 128;
  const int col0 = blockIdx.x * 128;
  const int sr = tid >> 1, sh = tid & 1;
  const unsigned short* ap = ysbf + (size_t)(row0 + sr) * 256 + sh * 16;
  const float* bp = WoP + (size_t)(col0 + sr) * 256 + sh * 16;
  unsigned short* wa = &lsA[sr * 40 + sh * 16];
  unsigned short* wb = &lsB[sr * 40 + sh * 16];

  const int lane = tid & 63;
  const int w = tid >> 6, wr = w >> 1, wc = w & 1;
  const int fr = lane & 15, fk = lane >> 4;

  f32x4 acc[4][4];
#pragma unroll
  for (int m = 0; m < 4; ++m)
#pragma unroll
    for (int n = 0; n < 4; ++n) acc[m][n] = (f32x4){0.f, 0.f, 0.f, 0.f};

  for (int kt = 0; kt < 8; ++kt) {
    u16x8 pa0 = *(const u16x8*)(ap + kt * 32);
    u16x8 pa1 = *(const u16x8*)(ap + kt * 32 + 8);
    const float* bq = bp + kt * 32;
    f32x4 B0 = *(const f32x4*)(bq + 0), B1 = *(const f32x4*)(bq + 4);
    f32x4 B2 = *(const f32x4*)(bq + 8), B3 = *(const f32x4*)(bq + 12);
    u16x8 pb0, pb1;
#pragma unroll
    for (int e = 0; e < 4; ++e) {
      pb0[e] = f2bf(B0[e]); pb0[e + 4] = f2bf(B1[e]);
      pb1[e] = f2bf(B2[e]); pb1[e + 4] = f2bf(B3[e]);
    }
    *(u16x8*)wa = pa0; *(u16x8*)(wa + 8) = pa1;
    *(u16x8*)wb = pb0; *(u16x8*)(wb + 8) = pb1;
    __syncthreads();
    bf16x8 af[4], bfr[4];
#pragma unroll
    for (int m = 0; m < 4; ++m)
      af[m] = *(const bf16x8*)(&lsA[(wr * 64 + m * 16 + fr) * 40 + fk * 8]);
#pragma unroll
    for (int n = 0; n < 4; ++n)
      bfr[n] = *(const bf16x8*)(&lsB[(wc * 64 + n * 16 + fr) * 40 + fk * 8]);
#pragma unroll
    for (int m = 0; m < 4; ++m)
#pragma unroll
      for (int n = 0; n < 4; ++n)
        acc[m][n] = __builtin_amdgcn_mfma_f32_16x16x32_bf16(af[m], bfr[n],
                                                            acc[m][n], 0, 0, 0);
    __syncthreads();
  }
#pragma unroll
  for (int m = 0; m < 4; ++m)
#pragma unroll
    for (int n = 0; n < 4; ++n) {
      const int col = col0 + wc * 64 + n * 16 + fr;
      const float bias = bo[col];
#pragma unroll
      for (int r = 0; r < 4; ++r) {
        const int row = row0 + wr * 64 + m * 16 + fk * 4 + r;
        out[(size_t)row * 1024 + col] = acc[m][n][r] + bias;
      }
    }
}

// ---------------------------------------------------------------------------
extern "C" void kernel_launch(void* const* d_in, const int* in_sizes, int n_in,
                              void* d_out, int out_size, void* d_ws, size_t ws_size,
                              hipStream_t stream) {
  const float* x = (const float*)d_in[0];
  const float* Wk = (const float*)d_in[1];
  const float* Wv = (const float*)d_in[2];
  const float* Wg = (const float*)d_in[3];
  const float* bg = (const float*)d_in[4];
  const float* Wo = (const float*)d_in[5];
  const float* bo = (const float*)d_in[6];

  float* out = (float*)d_out;                        // [8192][1024]
  float* err_out = out + (size_t)M_ROWS * 1024;      // [8192]

  char* ws = (char*)d_ws;
  float* KV = (float*)ws;                                        // 16 MB
  float* gate = (float*)(ws + (size_t)M_ROWS * 512 * 4);         // 32 KB
  unsigned short* ysbf =
      (unsigned short*)(ws + (size_t)M_ROWS * 512 * 4 + 32768);  // 4 MB
  float* WoP = (float*)(ws + (size_t)M_ROWS * 512 * 4 + 32768 +
                        (size_t)M_ROWS * 256 * 2);               // 1 MB
  float* actv = (float*)(ws + (size_t)M_ROWS * 512 * 4 + 32768 +
                         (size_t)M_ROWS * 256 * 2 + (size_t)1024 * 256 * 4); // 512 KB

  gemm_kv<<<dim3(4, 64), 256, 0, stream>>>(x, Wk, Wv, KV);
  act_kernel<<<dim3(512), 256, 0, stream>>>(KV, actv);
  gate_kernel<<<dim3(2048), 256, 0, stream>>>(x, Wg, bg, gate);
  wo_perm<<<dim3(1024), 256, 0, stream>>>(Wo, WoP);
  scan_kernel<<<dim3(8), 64, 0, stream>>>(KV, gate, actv, ysbf, err_out);
  gemm_out<<<dim3(8, 64), 256, 0, stream>>>(ysbf, WoP, bo, out);
}

// Round 10
// 851.970 us; speedup vs baseline: 1.3396x; 1.3396x over previous
//
#include <hip/hip_runtime.h>
#include <hip/hip_bf16.h>

#define B_DIM 8
#define S_DIM 1024
#define D_DIM 1024
#define N_DIM 256
#define M_ROWS (B_DIM * S_DIM) /* 8192 */

typedef __attribute__((ext_vector_type(8))) short bf16x8;
typedef __attribute__((ext_vector_type(8))) unsigned short u16x8;
typedef __attribute__((ext_vector_type(4))) float f32x4;

static __device__ __forceinline__ unsigned short f2bf(float f) {
  union { __hip_bfloat16 h; unsigned short s; } u;
  u.h = __float2bfloat16(f);
  return u.s;
}

static __device__ __forceinline__ float log1p_fast(float x) {
  return __logf(1.0f + x);
}

static __device__ __forceinline__ float hsum4(f32x4 v) {
  return (v[0] + v[1]) + (v[2] + v[3]);
}

// lane^1 exchange via DPP quad_perm [1,0,3,2] — pure VALU, no ds_bpermute.
static __device__ __forceinline__ float dpp_swap1(float x) {
  int r = __builtin_amdgcn_update_dpp(0, __builtin_bit_cast(int, x),
                                      0xB1, 0xF, 0xF, true);
  return __builtin_bit_cast(float, r);
}
static __device__ __forceinline__ float pair_sum(float x) {
  return x + dpp_swap1(x);
}

// Barrier that does NOT drain vmcnt: LDS visibility only.
#define LDS_BARRIER()                                         \
  do {                                                        \
    asm volatile("s_waitcnt lgkmcnt(0)" ::: "memory");        \
    __builtin_amdgcn_s_barrier();                             \
    asm volatile("" ::: "memory");                            \
  } while (0)

// ---------------------------------------------------------------------------
// GEMM1: KV[8192][512] = x[8192][1024] @ [Wk;Wv]([512][1024])^T   (bf16 MFMA)
// ---------------------------------------------------------------------------
__global__ __launch_bounds__(256) void gemm_kv(const float* __restrict__ x,
                                               const float* __restrict__ Wk,
                                               const float* __restrict__ Wv,
                                               float* __restrict__ KV) {
  __shared__ unsigned short lsA[128 * 40];
  __shared__ unsigned short lsB[128 * 40];
  const int tid = threadIdx.x;
  const int row0 = blockIdx.y * 128;
  const int col0 = blockIdx.x * 128;
  const float* Bsrc = (col0 < 256) ? (Wk + (size_t)col0 * 1024)
                                   : (Wv + (size_t)(col0 - 256) * 1024);
  const int sr = tid >> 1, sh = tid & 1;
  const float* ap = x + (size_t)(row0 + sr) * 1024 + sh * 16;
  const float* bp = Bsrc + (size_t)sr * 1024 + sh * 16;
  unsigned short* wa = &lsA[sr * 40 + sh * 16];
  unsigned short* wb = &lsB[sr * 40 + sh * 16];

  const int lane = tid & 63;
  const int w = tid >> 6, wr = w >> 1, wc = w & 1;
  const int fr = lane & 15, fk = lane >> 4;

  f32x4 acc[4][4];
#pragma unroll
  for (int m = 0; m < 4; ++m)
#pragma unroll
    for (int n = 0; n < 4; ++n) acc[m][n] = (f32x4){0.f, 0.f, 0.f, 0.f};

  for (int kt = 0; kt < 32; ++kt) {
    const float* a = ap + kt * 32;
    const float* b = bp + kt * 32;
    f32x4 A0 = *(const f32x4*)(a + 0), A1 = *(const f32x4*)(a + 4);
    f32x4 A2 = *(const f32x4*)(a + 8), A3 = *(const f32x4*)(a + 12);
    f32x4 B0 = *(const f32x4*)(b + 0), B1 = *(const f32x4*)(b + 4);
    f32x4 B2 = *(const f32x4*)(b + 8), B3 = *(const f32x4*)(b + 12);
    u16x8 pa0, pa1, pb0, pb1;
#pragma unroll
    for (int e = 0; e < 4; ++e) {
      pa0[e] = f2bf(A0[e]); pa0[e + 4] = f2bf(A1[e]);
      pa1[e] = f2bf(A2[e]); pa1[e + 4] = f2bf(A3[e]);
      pb0[e] = f2bf(B0[e]); pb0[e + 4] = f2bf(B1[e]);
      pb1[e] = f2bf(B2[e]); pb1[e + 4] = f2bf(B3[e]);
    }
    *(u16x8*)wa = pa0; *(u16x8*)(wa + 8) = pa1;
    *(u16x8*)wb = pb0; *(u16x8*)(wb + 8) = pb1;
    __syncthreads();
    bf16x8 af[4], bfr[4];
#pragma unroll
    for (int m = 0; m < 4; ++m)
      af[m] = *(const bf16x8*)(&lsA[(wr * 64 + m * 16 + fr) * 40 + fk * 8]);
#pragma unroll
    for (int n = 0; n < 4; ++n)
      bfr[n] = *(const bf16x8*)(&lsB[(wc * 64 + n * 16 + fr) * 40 + fk * 8]);
#pragma unroll
    for (int m = 0; m < 4; ++m)
#pragma unroll
      for (int n = 0; n < 4; ++n)
        acc[m][n] = __builtin_amdgcn_mfma_f32_16x16x32_bf16(af[m], bfr[n],
                                                            acc[m][n], 0, 0, 0);
    __syncthreads();
  }
#pragma unroll
  for (int m = 0; m < 4; ++m)
#pragma unroll
    for (int n = 0; n < 4; ++n) {
      const int col = col0 + wc * 64 + n * 16 + fr;
#pragma unroll
      for (int r = 0; r < 4; ++r) {
        const int row = row0 + wr * 64 + m * 16 + fk * 4 + r;
        KV[(size_t)row * 512 + col] = acc[m][n][r];
      }
    }
}

// ---------------------------------------------------------------------------
// gate[8192] = sigmoid(x @ Wg^T + bg)
// ---------------------------------------------------------------------------
__global__ __launch_bounds__(256) void gate_kernel(const float* __restrict__ x,
                                                   const float* __restrict__ Wg,
                                                   const float* __restrict__ bg,
                                                   float* __restrict__ gate) {
  const int row = blockIdx.x * 4 + (threadIdx.x >> 6);
  const int lane = threadIdx.x & 63;
  const f32x4* xr = (const f32x4*)(x + (size_t)row * 1024);
  const f32x4* wg = (const f32x4*)Wg;
  float s = 0.f;
#pragma unroll
  for (int c = 0; c < 4; ++c) {
    f32x4 a = xr[lane + 64 * c];
    f32x4 wv = wg[lane + 64 * c];
    s += a[0] * wv[0] + a[1] * wv[1] + a[2] * wv[2] + a[3] * wv[3];
  }
#pragma unroll
  for (int off = 32; off >= 1; off >>= 1) s += __shfl_xor(s, off, 64);
  if (lane == 0) gate[row] = 1.f / (1.f + __expf(-(s + bg[0])));
}

// ---------------------------------------------------------------------------
// WoP[d][i*16+k] = Wo[d][k*16+i]  (involution permute of columns)
// ---------------------------------------------------------------------------
__global__ __launch_bounds__(256) void wo_perm(const float* __restrict__ Wo,
                                               float* __restrict__ WoP) {
  const int d = blockIdx.x;
  const int c = threadIdx.x;
  WoP[(size_t)d * 256 + c] = Wo[(size_t)d * 256 + ((c & 15) * 16 + (c >> 4))];
}

// ---------------------------------------------------------------------------
// actv[b][s][i] = || K[b,s,i,:] ||  (scan-independent, precomputed)
// ---------------------------------------------------------------------------
__global__ __launch_bounds__(256) void act_kernel(const float* __restrict__ KV,
                                                  float* __restrict__ actv) {
  const int idx = blockIdx.x * 256 + threadIdx.x;  // 0..131071
  const int bs = idx >> 4, i = idx & 15;
  const f32x4* p = (const f32x4*)(KV + (size_t)bs * 512 + i * 16);
  f32x4 a0 = p[0], a1 = p[1], a2 = p[2], a3 = p[3];
  f32x4 s = a0 * a0 + a1 * a1 + a2 * a2 + a3 * a3;
  actv[idx] = sqrtf(hsum4(s));
}

// ---------------------------------------------------------------------------
// Sequential scan: 1 block per batch, 512 threads, thread (i,k,h):
// h in {0,1} owns j-slice [h*8, h*8+8). Native f32x4 math (compiler packs
// to v_pk_*_f32); cross-half combine via DPP quad_perm. 2 waves/SIMD.
// ---------------------------------------------------------------------------
__global__ __launch_bounds__(512) void scan_kernel(const float* __restrict__ KV,
                                                   const float* __restrict__ gate,
                                                   const float* __restrict__ actv,
                                                   unsigned short* __restrict__ ysbf,
                                                   float* __restrict__ err_out) {
  const int b = blockIdx.x;
  const int tid = threadIdx.x;       // 0..511
  const int i = tid >> 5;            // 0..15
  const int k = (tid >> 1) & 15;     // 0..15
  const int h = tid & 1;             // 0..1
  const int j0 = h * 8;

  __shared__ __align__(16) float hidT[2][16 * 20 + 4];  // [a][b] = hidden[b][a]
  __shared__ __align__(16) float errS[256];
  __shared__ __align__(16) float red[2][8];             // row-pair err^2 partials

  // weight slices: wXq[r][e] = wX[i][j0+4r+e][k];  eye addend
  f32x4 w1q[2], w2q[2], w2tq[2], eyeq[2];
#pragma unroll
  for (int r = 0; r < 2; ++r) {
    f32x4 v;
#pragma unroll
    for (int e = 0; e < 4; ++e) v[e] = ((j0 + 4 * r + e) == k) ? 1.f : 0.f;
    w1q[r] = v; w2q[r] = v; w2tq[r] = v; eyeq[r] = v;
  }
  float strength = 0.f, last_seen = 0.f, pend = 0.f;

  const float* Kb = KV + (size_t)b * S_DIM * 512;
  const float* Gb = gate + (size_t)b * S_DIM;
  const float* Ab = actv + (size_t)b * S_DIM * 16;
  unsigned short* Yb = ysbf + (size_t)b * S_DIM * 256;
  float* Eb = err_out + (size_t)b * S_DIM;

  // ping-pong prefetch buffers (depth 2)
  f32x4 kqA0, kqA1, kqB0, kqB1;
  float vtA, vtB, gA, gB, aA, aB;
  {
    kqA0 = *(const f32x4*)(Kb + i * 16 + j0);
    kqA1 = *(const f32x4*)(Kb + i * 16 + j0 + 4);
    vtA = Kb[256 + i * 16 + k]; gA = Gb[0]; aA = Ab[i];
    kqB0 = *(const f32x4*)(Kb + 512 + i * 16 + j0);
    kqB1 = *(const f32x4*)(Kb + 512 + i * 16 + j0 + 4);
    vtB = Kb[512 + 256 + i * 16 + k]; gB = Gb[1]; aB = Ab[16 + i];
  }

  auto step = [&](int s, f32x4& kq0, f32x4& kq1, float& vt, float& gv,
                  float& av) {
    const int pb = s & 1;
    const float t = (float)(s + 1);

    // hidden[i][k] = sum_j kt[i][j] * w1[i][j][k]  (f32x4 dot + DPP pair-sum)
    f32x4 hacc = kq0 * w1q[0] + kq1 * w1q[1];
    const float hidden = pair_sum(hsum4(hacc));
    if (h == 0) hidT[pb][k * 20 + i] = hidden;

    // pre-barrier scalar work
    const float delta = t - last_seen;
    const float m_pre = fmaxf(log1p_fast(delta * 0.1f), 1.f);
    const float pend_new = log1p_fast(delta) * av * gv * 0.05f;
    const bool seen = (av > 0.1f);

    LDS_BARRIER();

    // hj = hidden[j][i] for j in [j0, j0+8)
    const f32x4 hq0 = *(const f32x4*)&hidT[pb][i * 20 + j0];
    const f32x4 hq1 = *(const f32x4*)&hidT[pb][i * 20 + j0 + 4];
    const float hkk = hidT[pb][i * 20 + k];  // hidden[k][i]

    // strength update with step s-1's err_norm (8 row-pair partials)
    if (s > 0) {
      const f32x4* rp = (const f32x4*)&red[1 - pb][0];
      const f32x4 rs = rp[0] + rp[1];
      const float en = sqrtf(hsum4(rs));
      strength += pend * __builtin_amdgcn_rcpf(1.f + en);
      if (tid == 0) Eb[s - 1] = en;
    }
    const float df = 0.05f * m_pre * __builtin_amdgcn_rcpf(m_pre + strength);
    const float am = 1.f - df;

    // vt_pred[i][k] = sum_j hidden[j][i] * w2[i][j][k]
    f32x4 vacc = hq0 * w2q[0] + hq1 * w2q[1];
    const float vt_pred = pair_sum(hsum4(vacc));
    if (h == 0) Yb[(size_t)s * 256 + i * 16 + k] = f2bf(vt_pred);

    const float err = vt_pred - vt;

    // intra-wave err row exchange
    if (h == 0) errS[i * 16 + k] = err;
    asm volatile("s_waitcnt lgkmcnt(0)" ::: "memory");
    const f32x4 eq0 = *(const f32x4*)&errS[i * 16 + j0];
    const f32x4 eq1 = *(const f32x4*)&errS[i * 16 + j0 + 4];

    // per-row err^2 -> row-pair partial (shfl32 crosses the two rows in wave)
    const f32x4 eacc = eq0 * eq0 + eq1 * eq1;
    const float e2row = pair_sum(hsum4(eacc));
    const float e2pair = e2row + __shfl_xor(e2row, 32, 64);
    if ((tid & 63) == 0) red[pb][tid >> 6] = e2pair;

    // grad_h[i][k] = sum_j err[i][j] * w2[i][k][j]
    const f32x4 gacc = eq0 * w2tq[0] + eq1 * w2tq[1];
    const float gh = pair_sum(hsum4(gacc));

    const float slr = 0.1f * gv;
    const float nsg = -slr * gh;
    const float nse = -slr * err;
    const float nsh = -slr * hkk;
#pragma unroll
    for (int r = 0; r < 2; ++r) {
      const f32x4 kr = (r == 0) ? kq0 : kq1;
      const f32x4 hr = (r == 0) ? hq0 : hq1;
      const f32x4 er = (r == 0) ? eq0 : eq1;
      const f32x4 dfr = eyeq[r] * df;
      w1q[r] = (w1q[r] + nsg * kr) * am + dfr;
      w2q[r] = (w2q[r] + nse * hr) * am + dfr;
      w2tq[r] = (w2tq[r] + nsh * er) * am + dfr;
    }

    pend = pend_new;
    if (seen) last_seen = t;

    // prefetch step s+2 (stray tail reads stay inside ws)
    {
      const float* base = Kb + (size_t)(s + 2) * 512;
      kq0 = *(const f32x4*)(base + i * 16 + j0);
      kq1 = *(const f32x4*)(base + i * 16 + j0 + 4);
      vt = base[256 + i * 16 + k];
      gv = Gb[s + 2];
      av = Ab[(size_t)(s + 2) * 16 + i];
    }
  };

  for (int s = 0; s < S_DIM; s += 2) {
    step(s, kqA0, kqA1, vtA, gA, aA);
    step(s + 1, kqB0, kqB1, vtB, gB, aB);
  }
  LDS_BARRIER();
  if (tid == 0) {
    const f32x4* rp = (const f32x4*)&red[1][0];  // s=1023 parity = 1
    const f32x4 rs = rp[0] + rp[1];
    Eb[S_DIM - 1] = sqrtf(hsum4(rs));
  }
}

// ---------------------------------------------------------------------------
// GEMM2: out[8192][1024] = ysP[8192][256](bf16) @ WoP([1024][256])^T + bo
// ---------------------------------------------------------------------------
__global__ __launch_bounds__(256) void gemm_out(const unsigned short* __restrict__ ysbf,
                                                const float* __restrict__ WoP,
                                                const float* __restrict__ bo,
                                                float* __restrict__ out) {
  __shared__ unsigned short lsA[128 * 40];
  __shared__ unsigned short lsB[128 * 40];
  const int tid = threadIdx.x;
  const int row0 = blockIdx.y * 128;
  const int col0 = blockIdx.x * 128;
  const int sr = tid >> 1, sh = tid & 1;
  const unsigned short* ap = ysbf + (size_t)(row0 + sr) * 256 + sh * 16;
  const float* bp = WoP + (size_t)(col0 + sr) * 256 + sh * 16;
  unsigned short* wa = &lsA[sr * 40 + sh * 16];
  unsigned short* wb = &lsB[sr * 40 + sh * 16];

  const int lane = tid & 63;
  const int w = tid >> 6, wr = w >> 1, wc = w & 1;
  const int fr = lane & 15, fk = lane >> 4;

  f32x4 acc[4][4];
#pragma unroll
  for (int m = 0; m < 4; ++m)
#pragma unroll
    for (int n = 0; n < 4; ++n) acc[m][n] = (f32x4){0.f, 0.f, 0.f, 0.f};

  for (int kt = 0; kt < 8; ++kt) {
    u16x8 pa0 = *(const u16x8*)(ap + kt * 32);
    u16x8 pa1 = *(const u16x8*)(ap + kt * 32 + 8);
    const float* bq = bp + kt * 32;
    f32x4 B0 = *(const f32x4*)(bq + 0), B1 = *(const f32x4*)(bq + 4);
    f32x4 B2 = *(const f32x4*)(bq + 8), B3 = *(const f32x4*)(bq + 12);
    u16x8 pb0, pb1;
#pragma unroll
    for (int e = 0; e < 4; ++e) {
      pb0[e] = f2bf(B0[e]); pb0[e + 4] = f2bf(B1[e]);
      pb1[e] = f2bf(B2[e]); pb1[e + 4] = f2bf(B3[e]);
    }
    *(u16x8*)wa = pa0; *(u16x8*)(wa + 8) = pa1;
    *(u16x8*)wb = pb0; *(u16x8*)(wb + 8) = pb1;
    __syncthreads();
    bf16x8 af[4], bfr[4];
#pragma unroll
    for (int m = 0; m < 4; ++m)
      af[m] = *(const bf16x8*)(&lsA[(wr * 64 + m * 16 + fr) * 40 + fk * 8]);
#pragma unroll
    for (int n = 0; n < 4; ++n)
      bfr[n] = *(const bf16x8*)(&lsB[(wc * 64 + n * 16 + fr) * 40 + fk * 8]);
#pragma unroll
    for (int m = 0; m < 4; ++m)
#pragma unroll
      for (int n = 0; n < 4; ++n)
        acc[m][n] = __builtin_amdgcn_mfma_f32_16x16x32_bf16(af[m], bfr[n],
                                                            acc[m][n], 0, 0, 0);
    __syncthreads();
  }
#pragma unroll
  for (int m = 0; m < 4; ++m)
#pragma unroll
    for (int n = 0; n < 4; ++n) {
      const int col = col0 + wc * 64 + n * 16 + fr;
      const float bias = bo[col];
#pragma unroll
      for (int r = 0; r < 4; ++r) {
        const int row = row0 + wr * 64 + m * 16 + fk * 4 + r;
        out[(size_t)row * 1024 + col] = acc[m][n][r] + bias;
      }
    }
}

// ---------------------------------------------------------------------------
extern "C" void kernel_launch(void* const* d_in, const int* in_sizes, int n_in,
                              void* d_out, int out_size, void* d_ws, size_t ws_size,
                              hipStream_t stream) {
  const float* x = (const float*)d_in[0];
  const float* Wk = (const float*)d_in[1];
  const float* Wv = (const float*)d_in[2];
  const float* Wg = (const float*)d_in[3];
  const float* bg = (const float*)d_in[4];
  const float* Wo = (const float*)d_in[5];
  const float* bo = (const float*)d_in[6];

  float* out = (float*)d_out;                        // [8192][1024]
  float* err_out = out + (size_t)M_ROWS * 1024;      // [8192]

  char* ws = (char*)d_ws;
  float* KV = (float*)ws;                                        // 16 MB
  float* gate = (float*)(ws + (size_t)M_ROWS * 512 * 4);         // 32 KB
  unsigned short* ysbf =
      (unsigned short*)(ws + (size_t)M_ROWS * 512 * 4 + 32768);  // 4 MB
  float* WoP = (float*)(ws + (size_t)M_ROWS * 512 * 4 + 32768 +
                        (size_t)M_ROWS * 256 * 2);               // 1 MB
  float* actv = (float*)(ws + (size_t)M_ROWS * 512 * 4 + 32768 +
                         (size_t)M_ROWS * 256 * 2 + (size_t)1024 * 256 * 4); // 512 KB

  gemm_kv<<<dim3(4, 64), 256, 0, stream>>>(x, Wk, Wv, KV);
  act_kernel<<<dim3(512), 256, 0, stream>>>(KV, actv);
  gate_kernel<<<dim3(2048), 256, 0, stream>>>(x, Wg, bg, gate);
  wo_perm<<<dim3(1024), 256, 0, stream>>>(Wo, WoP);
  scan_kernel<<<dim3(8), 512, 0, stream>>>(KV, gate, actv, ysbf, err_out);
  gemm_out<<<dim3(8, 64), 256, 0, stream>>>(ysbf, WoP, bo, out);
}

// Round 11
// 821.465 us; speedup vs baseline: 1.3893x; 1.0371x over previous
//
#include <hip/hip_runtime.h>
#include <hip/hip_bf16.h>

#define B_DIM 8
#define S_DIM 1024
#define D_DIM 1024
#define N_DIM 256
#define M_ROWS (B_DIM * S_DIM) /* 8192 */

typedef __attribute__((ext_vector_type(8))) short bf16x8;
typedef __attribute__((ext_vector_type(8))) unsigned short u16x8;
typedef __attribute__((ext_vector_type(4))) float f32x4;
typedef __attribute__((ext_vector_type(2))) float f32x2;

static __device__ __forceinline__ unsigned short f2bf(float f) {
  union { __hip_bfloat16 h; unsigned short s; } u;
  u.h = __float2bfloat16(f);
  return u.s;
}

static __device__ __forceinline__ float log1p_fast(float x) {
  return __logf(1.0f + x);
}

// packed-half horizontal sum: 1 pk add + 1 scalar add
static __device__ __forceinline__ float hsum4(f32x4 v) {
  f32x2 lo = {v[0], v[1]}, hi = {v[2], v[3]};
  f32x2 t = lo + hi;
  return t[0] + t[1];
}

// lane^1 exchange via DPP quad_perm [1,0,3,2] — pure VALU, no ds_bpermute.
static __device__ __forceinline__ float dpp_swap1(float x) {
  int r = __builtin_amdgcn_update_dpp(0, __builtin_bit_cast(int, x),
                                      0xB1, 0xF, 0xF, true);
  return __builtin_bit_cast(float, r);
}
static __device__ __forceinline__ float pair_sum(float x) {
  return x + dpp_swap1(x);
}

// Barrier that does NOT drain vmcnt: LDS visibility only.
#define LDS_BARRIER()                                         \
  do {                                                        \
    asm volatile("s_waitcnt lgkmcnt(0)" ::: "memory");        \
    __builtin_amdgcn_s_barrier();                             \
    asm volatile("" ::: "memory");                            \
  } while (0)

// ---------------------------------------------------------------------------
// GEMM1: KV[8192][512] = x[8192][1024] @ [Wk;Wv]([512][1024])^T   (bf16 MFMA)
// ---------------------------------------------------------------------------
__global__ __launch_bounds__(256) void gemm_kv(const float* __restrict__ x,
                                               const float* __restrict__ Wk,
                                               const float* __restrict__ Wv,
                                               float* __restrict__ KV) {
  __shared__ unsigned short lsA[128 * 40];
  __shared__ unsigned short lsB[128 * 40];
  const int tid = threadIdx.x;
  const int row0 = blockIdx.y * 128;
  const int col0 = blockIdx.x * 128;
  const float* Bsrc = (col0 < 256) ? (Wk + (size_t)col0 * 1024)
                                   : (Wv + (size_t)(col0 - 256) * 1024);
  const int sr = tid >> 1, sh = tid & 1;
  const float* ap = x + (size_t)(row0 + sr) * 1024 + sh * 16;
  const float* bp = Bsrc + (size_t)sr * 1024 + sh * 16;
  unsigned short* wa = &lsA[sr * 40 + sh * 16];
  unsigned short* wb = &lsB[sr * 40 + sh * 16];

  const int lane = tid & 63;
  const int w = tid >> 6, wr = w >> 1, wc = w & 1;
  const int fr = lane & 15, fk = lane >> 4;

  f32x4 acc[4][4];
#pragma unroll
  for (int m = 0; m < 4; ++m)
#pragma unroll
    for (int n = 0; n < 4; ++n) acc[m][n] = (f32x4){0.f, 0.f, 0.f, 0.f};

  for (int kt = 0; kt < 32; ++kt) {
    const float* a = ap + kt * 32;
    const float* b = bp + kt * 32;
    f32x4 A0 = *(const f32x4*)(a + 0), A1 = *(const f32x4*)(a + 4);
    f32x4 A2 = *(const f32x4*)(a + 8), A3 = *(const f32x4*)(a + 12);
    f32x4 B0 = *(const f32x4*)(b + 0), B1 = *(const f32x4*)(b + 4);
    f32x4 B2 = *(const f32x4*)(b + 8), B3 = *(const f32x4*)(b + 12);
    u16x8 pa0, pa1, pb0, pb1;
#pragma unroll
    for (int e = 0; e < 4; ++e) {
      pa0[e] = f2bf(A0[e]); pa0[e + 4] = f2bf(A1[e]);
      pa1[e] = f2bf(A2[e]); pa1[e + 4] = f2bf(A3[e]);
      pb0[e] = f2bf(B0[e]); pb0[e + 4] = f2bf(B1[e]);
      pb1[e] = f2bf(B2[e]); pb1[e + 4] = f2bf(B3[e]);
    }
    *(u16x8*)wa = pa0; *(u16x8*)(wa + 8) = pa1;
    *(u16x8*)wb = pb0; *(u16x8*)(wb + 8) = pb1;
    __syncthreads();
    bf16x8 af[4], bfr[4];
#pragma unroll
    for (int m = 0; m < 4; ++m)
      af[m] = *(const bf16x8*)(&lsA[(wr * 64 + m * 16 + fr) * 40 + fk * 8]);
#pragma unroll
    for (int n = 0; n < 4; ++n)
      bfr[n] = *(const bf16x8*)(&lsB[(wc * 64 + n * 16 + fr) * 40 + fk * 8]);
#pragma unroll
    for (int m = 0; m < 4; ++m)
#pragma unroll
      for (int n = 0; n < 4; ++n)
        acc[m][n] = __builtin_amdgcn_mfma_f32_16x16x32_bf16(af[m], bfr[n],
                                                            acc[m][n], 0, 0, 0);
    __syncthreads();
  }
#pragma unroll
  for (int m = 0; m < 4; ++m)
#pragma unroll
    for (int n = 0; n < 4; ++n) {
      const int col = col0 + wc * 64 + n * 16 + fr;
#pragma unroll
      for (int r = 0; r < 4; ++r) {
        const int row = row0 + wr * 64 + m * 16 + fk * 4 + r;
        KV[(size_t)row * 512 + col] = acc[m][n][r];
      }
    }
}

// ---------------------------------------------------------------------------
// gate[8192] = sigmoid(x @ Wg^T + bg)
// ---------------------------------------------------------------------------
__global__ __launch_bounds__(256) void gate_kernel(const float* __restrict__ x,
                                                   const float* __restrict__ Wg,
                                                   const float* __restrict__ bg,
                                                   float* __restrict__ gate) {
  const int row = blockIdx.x * 4 + (threadIdx.x >> 6);
  const int lane = threadIdx.x & 63;
  const f32x4* xr = (const f32x4*)(x + (size_t)row * 1024);
  const f32x4* wg = (const f32x4*)Wg;
  float s = 0.f;
#pragma unroll
  for (int c = 0; c < 4; ++c) {
    f32x4 a = xr[lane + 64 * c];
    f32x4 wv = wg[lane + 64 * c];
    s += a[0] * wv[0] + a[1] * wv[1] + a[2] * wv[2] + a[3] * wv[3];
  }
#pragma unroll
  for (int off = 32; off >= 1; off >>= 1) s += __shfl_xor(s, off, 64);
  if (lane == 0) gate[row] = 1.f / (1.f + __expf(-(s + bg[0])));
}

// ---------------------------------------------------------------------------
// WoP[d][i*16+k] = Wo[d][k*16+i]  (involution permute of columns)
// ---------------------------------------------------------------------------
__global__ __launch_bounds__(256) void wo_perm(const float* __restrict__ Wo,
                                               float* __restrict__ WoP) {
  const int d = blockIdx.x;
  const int c = threadIdx.x;
  WoP[(size_t)d * 256 + c] = Wo[(size_t)d * 256 + ((c & 15) * 16 + (c >> 4))];
}

// ---------------------------------------------------------------------------
// actv[b][s][i] = || K[b,s,i,:] ||  (scan-independent, precomputed)
// ---------------------------------------------------------------------------
__global__ __launch_bounds__(256) void act_kernel(const float* __restrict__ KV,
                                                  float* __restrict__ actv) {
  const int idx = blockIdx.x * 256 + threadIdx.x;  // 0..131071
  const int bs = idx >> 4, i = idx & 15;
  const f32x4* p = (const f32x4*)(KV + (size_t)bs * 512 + i * 16);
  f32x4 a0 = p[0], a1 = p[1], a2 = p[2], a3 = p[3];
  f32x4 s = a0 * a0 + a1 * a1 + a2 * a2 + a3 * a3;
  actv[idx] = sqrtf(hsum4(s));
}

// ---------------------------------------------------------------------------
// Sequential scan: 1 block per batch, 512 threads, thread (i,k,h):
// h in {0,1} owns j-slice [h*8, h*8+8). Native f32x4 math, DPP pair combine,
// incremental pointers, branch-light. 2 waves/SIMD.
// ---------------------------------------------------------------------------
__global__ __launch_bounds__(512) void scan_kernel(const float* __restrict__ KV,
                                                   const float* __restrict__ gate,
                                                   const float* __restrict__ actv,
                                                   unsigned short* __restrict__ ysbf,
                                                   float* __restrict__ err_out) {
  const int b = blockIdx.x;
  const int tid = threadIdx.x;       // 0..511
  const int i = tid >> 5;            // 0..15
  const int k = (tid >> 1) & 15;     // 0..15
  const int h = tid & 1;             // 0..1
  const int j0 = h * 8;

  __shared__ __align__(16) float hidT[2][16 * 20 + 4];  // [a][b] = hidden[b][a]
  __shared__ __align__(16) float errS[256];
  __shared__ __align__(16) float red[2][8];             // row-pair err^2 partials

  if (tid < 16) ((float*)red)[tid] = 0.f;  // step-0 reads red[1] -> en = 0

  // weight slices: wXq[r][e] = wX[i][j0+4r+e][k];  eye addend
  f32x4 w1q[2], w2q[2], w2tq[2], eyeq[2];
#pragma unroll
  for (int r = 0; r < 2; ++r) {
    f32x4 v;
#pragma unroll
    for (int e = 0; e < 4; ++e) v[e] = ((j0 + 4 * r + e) == k) ? 1.f : 0.f;
    w1q[r] = v; w2q[r] = v; w2tq[r] = v; eyeq[r] = v;
  }
  float strength = 0.f, last_seen = 0.f, pend = 0.f;

  const float* Kb = KV + (size_t)b * S_DIM * 512;
  const float* Gb = gate + (size_t)b * S_DIM;
  const float* Ab = actv + (size_t)b * S_DIM * 16;
  float* Eb = err_out + (size_t)b * S_DIM;

  const int offK = i * 16 + j0;
  const int offV = 256 + i * 16 + k;

  // ping-pong prefetch buffers (depth 2)
  f32x4 kqA0, kqA1, kqB0, kqB1;
  float vtA, vtB, gA, gB, aA, aB;
  {
    kqA0 = *(const f32x4*)(Kb + offK);
    kqA1 = *(const f32x4*)(Kb + offK + 4);
    vtA = Kb[offV]; gA = Gb[0]; aA = Ab[i];
    kqB0 = *(const f32x4*)(Kb + 512 + offK);
    kqB1 = *(const f32x4*)(Kb + 512 + offK + 4);
    vtB = Kb[512 + offV]; gB = Gb[1]; aB = Ab[16 + i];
  }

  // rolling pointers (advance by one step's stride inside step())
  const float* pPre = Kb + 1024;                         // source for s+2
  const float* pG = Gb + 2;
  const float* pA = Ab + 32 + i;
  unsigned short* pY = ysbf + (size_t)b * S_DIM * 256 + i * 16 + k;

  auto step = [&](int s, f32x4& kq0, f32x4& kq1, float& vt, float& gv,
                  float& av) {
    const int pb = s & 1;
    const float t = (float)(s + 1);

    // hidden[i][k] = sum_j kt[i][j] * w1[i][j][k]  (f32x4 dot + DPP pair-sum)
    f32x4 hacc = kq0 * w1q[0] + kq1 * w1q[1];
    const float hidden = pair_sum(hsum4(hacc));
    hidT[pb][k * 20 + i] = hidden;  // both h lanes: same value, same addr

    // pre-barrier scalar work
    const float delta = t - last_seen;
    const float m_pre = fmaxf(log1p_fast(delta * 0.1f), 1.f);
    const float pend_new = log1p_fast(delta) * av * gv * 0.05f;
    const bool seen = (av > 0.1f);

    LDS_BARRIER();

    // hj = hidden[j][i] for j in [j0, j0+8)
    const f32x4 hq0 = *(const f32x4*)&hidT[pb][i * 20 + j0];
    const f32x4 hq1 = *(const f32x4*)&hidT[pb][i * 20 + j0 + 4];
    const float hkk = hidT[pb][i * 20 + k];  // hidden[k][i]

    // strength update with previous step's err_norm (branchless; red=0 at s=0)
    {
      const f32x4* rp = (const f32x4*)&red[1 - pb][0];
      const f32x4 rs = rp[0] + rp[1];
      const float en = sqrtf(hsum4(rs));
      strength += pend * __builtin_amdgcn_rcpf(1.f + en);
      if (tid == 0 && s != 0) Eb[s - 1] = en;
    }
    const float df = 0.05f * m_pre * __builtin_amdgcn_rcpf(m_pre + strength);
    const float am = 1.f - df;

    // vt_pred[i][k] = sum_j hidden[j][i] * w2[i][j][k]
    f32x4 vacc = hq0 * w2q[0] + hq1 * w2q[1];
    const float vt_pred = pair_sum(hsum4(vacc));
    *pY = f2bf(vt_pred);  // both h lanes: same value, same addr

    const float err = vt_pred - vt;

    // intra-wave err row exchange (same value from both h lanes)
    errS[i * 16 + k] = err;
    asm volatile("s_waitcnt lgkmcnt(0)" ::: "memory");
    const f32x4 eq0 = *(const f32x4*)&errS[i * 16 + j0];
    const f32x4 eq1 = *(const f32x4*)&errS[i * 16 + j0 + 4];

    // per-row err^2 -> row-pair partial (shfl32 crosses the two rows in wave)
    const f32x4 eacc = eq0 * eq0 + eq1 * eq1;
    const float e2row = pair_sum(hsum4(eacc));
    const float e2pair = e2row + __shfl_xor(e2row, 32, 64);
    if ((tid & 63) == 0) red[pb][tid >> 6] = e2pair;

    // grad_h[i][k] = sum_j err[i][j] * w2[i][k][j]
    const f32x4 gacc = eq0 * w2tq[0] + eq1 * w2tq[1];
    const float gh = pair_sum(hsum4(gacc));

    // 2-fma weight update: w = w*am + (x*(ns*am) + dfr)
    const float slr = 0.1f * gv;
    const float nsga = -slr * gh * am;
    const float nsea = -slr * err * am;
    const float nsha = -slr * hkk * am;
#pragma unroll
    for (int r = 0; r < 2; ++r) {
      const f32x4 kr = (r == 0) ? kq0 : kq1;
      const f32x4 hr = (r == 0) ? hq0 : hq1;
      const f32x4 er = (r == 0) ? eq0 : eq1;
      const f32x4 dfr = eyeq[r] * df;
      w1q[r] = w1q[r] * am + (kr * nsga + dfr);
      w2q[r] = w2q[r] * am + (hr * nsea + dfr);
      w2tq[r] = w2tq[r] * am + (er * nsha + dfr);
    }

    pend = pend_new;
    if (seen) last_seen = t;

    // prefetch step s+2 via rolling pointers (tail reads stay inside ws)
    kq0 = *(const f32x4*)(pPre + offK);
    kq1 = *(const f32x4*)(pPre + offK + 4);
    vt = pPre[offV];
    gv = *pG;
    av = *pA;
    pPre += 512; pG += 1; pA += 16; pY += 256;
  };

  for (int s = 0; s < S_DIM; s += 2) {
    step(s, kqA0, kqA1, vtA, gA, aA);
    step(s + 1, kqB0, kqB1, vtB, gB, aB);
  }
  LDS_BARRIER();
  if (tid == 0) {
    const f32x4* rp = (const f32x4*)&red[1][0];  // s=1023 parity = 1
    const f32x4 rs = rp[0] + rp[1];
    Eb[S_DIM - 1] = sqrtf(hsum4(rs));
  }
}

// ---------------------------------------------------------------------------
// GEMM2: out[8192][1024] = ysP[8192][256](bf16) @ WoP([1024][256])^T + bo
// ---------------------------------------------------------------------------
__global__ __launch_bounds__(256) void gemm_out(const unsigned short* __restrict__ ysbf,
                                                const float* __restrict__ WoP,
                                                const float* __restrict__ bo,
                                                float* __restrict__ out) {
  __shared__ unsigned short lsA[128 * 40];
  __shared__ unsigned short lsB[128 * 40];
  const int tid = threadIdx.x;
  const int row0 = blockIdx.y * 128;
  const int col0 = blockIdx.x * 128;
  const int sr = tid >> 1, sh = tid & 1;
  const unsigned short* ap = ysbf + (size_t)(row0 + sr) * 256 + sh * 16;
  const float* bp = WoP + (size_t)(col0 + sr) * 256 + sh * 16;
  unsigned short* wa = &lsA[sr * 40 + sh * 16];
  unsigned short* wb = &lsB[sr * 40 + sh * 16];

  const int lane = tid & 63;
  const int w = tid >> 6, wr = w >> 1, wc = w & 1;
  const int fr = lane & 15, fk = lane >> 4;

  f32x4 acc[4][4];
#pragma unroll
  for (int m = 0; m < 4; ++m)
#pragma unroll
    for (int n = 0; n < 4; ++n) acc[m][n] = (f32x4){0.f, 0.f, 0.f, 0.f};

  for (int kt = 0; kt < 8; ++kt) {
    u16x8 pa0 = *(const u16x8*)(ap + kt * 32);
    u16x8 pa1 = *(const u16x8*)(ap + kt * 32 + 8);
    const float* bq = bp + kt * 32;
    f32x4 B0 = *(const f32x4*)(bq + 0), B1 = *(const f32x4*)(bq + 4);
    f32x4 B2 = *(const f32x4*)(bq + 8), B3 = *(const f32x4*)(bq + 12);
    u16x8 pb0, pb1;
#pragma unroll
    for (int e = 0; e < 4; ++e) {
      pb0[e] = f2bf(B0[e]); pb0[e + 4] = f2bf(B1[e]);
      pb1[e] = f2bf(B2[e]); pb1[e + 4] = f2bf(B3[e]);
    }
    *(u16x8*)wa = pa0; *(u16x8*)(wa + 8) = pa1;
    *(u16x8*)wb = pb0; *(u16x8*)(wb + 8) = pb1;
    __syncthreads();
    bf16x8 af[4], bfr[4];
#pragma unroll
    for (int m = 0; m < 4; ++m)
      af[m] = *(const bf16x8*)(&lsA[(wr * 64 + m * 16 + fr) * 40 + fk * 8]);
#pragma unroll
    for (int n = 0; n < 4; ++n)
      bfr[n] = *(const bf16x8*)(&lsB[(wc * 64 + n * 16 + fr) * 40 + fk * 8]);
#pragma unroll
    for (int m = 0; m < 4; ++m)
#pragma unroll
      for (int n = 0; n < 4; ++n)
        acc[m][n] = __builtin_amdgcn_mfma_f32_16x16x32_bf16(af[m], bfr[n],
                                                            acc[m][n], 0, 0, 0);
    __syncthreads();
  }
#pragma unroll
  for (int m = 0; m < 4; ++m)
#pragma unroll
    for (int n = 0; n < 4; ++n) {
      const int col = col0 + wc * 64 + n * 16 + fr;
      const float bias = bo[col];
#pragma unroll
      for (int r = 0; r < 4; ++r) {
        const int row = row0 + wr * 64 + m * 16 + fk * 4 + r;
        out[(size_t)row * 1024 + col] = acc[m][n][r] + bias;
      }
    }
}

// ---------------------------------------------------------------------------
extern "C" void kernel_launch(void* const* d_in, const int* in_sizes, int n_in,
                              void* d_out, int out_size, void* d_ws, size_t ws_size,
                              hipStream_t stream) {
  const float* x = (const float*)d_in[0];
  const float* Wk = (const float*)d_in[1];
  const float* Wv = (const float*)d_in[2];
  const float* Wg = (const float*)d_in[3];
  const float* bg = (const float*)d_in[4];
  const float* Wo = (const float*)d_in[5];
  const float* bo = (const float*)d_in[6];

  float* out = (float*)d_out;                        // [8192][1024]
  float* err_out = out + (size_t)M_ROWS * 1024;      // [8192]

  // layout: KV | gate | ysbf | actv | WoP   (actv not last: tail prefetch pads)
  char* ws = (char*)d_ws;
  float* KV = (float*)ws;                                         // 16 MB
  float* gate = (float*)(ws + (size_t)M_ROWS * 512 * 4);          // 32 KB
  unsigned short* ysbf =
      (unsigned short*)(ws + (size_t)M_ROWS * 512 * 4 + 32768);   // 4 MB
  float* actv = (float*)(ws + (size_t)M_ROWS * 512 * 4 + 32768 +
                         (size_t)M_ROWS * 256 * 2);               // 512 KB
  float* WoP = (float*)(ws + (size_t)M_ROWS * 512 * 4 + 32768 +
                        (size_t)M_ROWS * 256 * 2 + (size_t)M_ROWS * 16 * 4);

  gemm_kv<<<dim3(4, 64), 256, 0, stream>>>(x, Wk, Wv, KV);
  act_kernel<<<dim3(512), 256, 0, stream>>>(KV, actv);
  gate_kernel<<<dim3(2048), 256, 0, stream>>>(x, Wg, bg, gate);
  wo_perm<<<dim3(1024), 256, 0, stream>>>(Wo, WoP);
  scan_kernel<<<dim3(8), 512, 0, stream>>>(KV, gate, actv, ysbf, err_out);
  gemm_out<<<dim3(8, 64), 256, 0, stream>>>(ysbf, WoP, bo, out);
}